// Round 8
// baseline (348.897 us; speedup 1.0000x reference)
//
#include <hip/hip_runtime.h>

typedef __attribute__((ext_vector_type(4))) float f32x4;
typedef __attribute__((ext_vector_type(8))) short s16x8;
typedef __attribute__((ext_vector_type(4))) int i32x4;
typedef __attribute__((ext_vector_type(4))) unsigned short u16x4;

#define NEG_INF_F (-9.0e15f)
#define LOG2E_F 1.44269504088896340736f
#define N_ROWS 8192
#define F_DIM 256

__device__ __forceinline__ unsigned short f2bf(float f) {
    unsigned int u = __builtin_bit_cast(unsigned int, f);
    u += 0x7fffu + ((u >> 16) & 1u);   // round-to-nearest-even
    return (unsigned short)(u >> 16);
}

// ------------- Kernel 0: pack adj (int32 0/1, 256MB) -> bitmask (8MB) ----
// Cross-lane-free: thread w builds u32 word w from its own contiguous 128B.
// Bit j of mask32[w] = (adj[w*32 + j] > 0). Verified equivalent to ballot (r6==r7).
__global__ __launch_bounds__(256) void k0_pack(const int* __restrict__ adj,
                                               unsigned* __restrict__ mask32) {
    const int t0 = (int)blockIdx.x * 256 + (int)threadIdx.x;
    const int nt = (int)gridDim.x * 256;
#pragma unroll 1
    for (int w = t0; w < (N_ROWS * N_ROWS / 32); w += nt) {
        const int* p = adj + (size_t)w * 32;
        unsigned m = 0;
#pragma unroll
        for (int i = 0; i < 8; ++i) {
            i32x4 v = *(const i32x4*)(p + i * 4);
            m |= (v[0] > 0 ? 1u : 0u) << (i * 4);
            m |= (v[1] > 0 ? 2u : 0u) << (i * 4);
            m |= (v[2] > 0 ? 4u : 0u) << (i * 4);
            m |= (v[3] > 0 ? 8u : 0u) << (i * 4);
        }
        mask32[w] = m;
    }
}

// ------------- Kernel 1: hT = bf16(x @ W^T)^T  [256][8192] ---------------
__global__ __launch_bounds__(256) void k1_gemm(const float* __restrict__ x,
                                               const float* __restrict__ W,
                                               unsigned short* __restrict__ hT) {
    __shared__ float xT[128][64];
    __shared__ float wT[128][64];
    const int tid = threadIdx.x;
    const int rb = blockIdx.x >> 2, fbk = blockIdx.x & 3;
    const int row0 = rb * 64, f0 = fbk * 64;
    const int rs = tid >> 2, cs = tid & 3;
    const int r0 = (tid & 15) * 4, fc = (tid >> 4) * 4;
    float acc[4][4];
#pragma unroll
    for (int i = 0; i < 4; ++i)
#pragma unroll
        for (int j = 0; j < 4; ++j) acc[i][j] = 0.0f;

#pragma unroll 1
    for (int p = 0; p < 2; ++p) {
        const int kb = p * 128;
        if (p) __syncthreads();
        const float* xrow = x + (size_t)(row0 + rs) * F_DIM + kb + cs * 32;
        const float* wrow = W + (size_t)(f0 + rs) * F_DIM + kb + cs * 32;
#pragma unroll
        for (int i = 0; i < 8; ++i) {
            f32x4 xv = *(const f32x4*)(xrow + i * 4);
            f32x4 wv = *(const f32x4*)(wrow + i * 4);
#pragma unroll
            for (int jj = 0; jj < 4; ++jj) {
                xT[cs * 32 + i * 4 + jj][rs] = xv[jj];
                wT[cs * 32 + i * 4 + jj][rs] = wv[jj];
            }
        }
        __syncthreads();
#pragma unroll 4
        for (int kk = 0; kk < 128; ++kk) {
            f32x4 xv = *(const f32x4*)&xT[kk][r0];
            f32x4 wv = *(const f32x4*)&wT[kk][fc];
#pragma unroll
            for (int i = 0; i < 4; ++i)
#pragma unroll
                for (int j = 0; j < 4; ++j)
                    acc[i][j] = fmaf(xv[i], wv[j], acc[i][j]);
        }
    }
#pragma unroll
    for (int j = 0; j < 4; ++j) {
        u16x4 t;
        t[0] = f2bf(acc[0][j]); t[1] = f2bf(acc[1][j]);
        t[2] = f2bf(acc[2][j]); t[3] = f2bf(acc[3][j]);
        *(u16x4*)(hT + (size_t)(f0 + fc + j) * N_ROWS + row0 + r0) = t;
    }
}

// ------------- Kernel 1a: va1 = W^T a1, va2 = W^T a2 ---------------------
__global__ __launch_bounds__(256) void kva(const float* __restrict__ W,
                                           const float* __restrict__ a,
                                           float* __restrict__ va) {
    const int k = threadIdx.x;              // 0..255
    const int b = blockIdx.x;               // 0: a1, 1: a2
    const float* av = a + b * 256;
    float s0 = 0.f, s1 = 0.f, s2 = 0.f, s3 = 0.f;
#pragma unroll 8
    for (int f = 0; f < 256; f += 4) {
        s0 = fmaf(av[f],     W[(size_t)f * 256 + k],       s0);
        s1 = fmaf(av[f + 1], W[(size_t)(f + 1) * 256 + k], s1);
        s2 = fmaf(av[f + 2], W[(size_t)(f + 2) * 256 + k], s2);
        s3 = fmaf(av[f + 3], W[(size_t)(f + 3) * 256 + k], s3);
    }
    va[b * 256 + k] = (s0 + s1) + (s2 + s3);
}

// ------------- Kernel 1b: s1 = x@va1, s2 = x@va2 (f32) -------------------
__global__ __launch_bounds__(256) void k1b_s(const float* __restrict__ x,
                                             const float* __restrict__ va,
                                             float* __restrict__ s1,
                                             float* __restrict__ s2) {
    const int tid = threadIdx.x, lane = tid & 63, w = tid >> 6;
    f32x4 a1 = *(const f32x4*)(va + lane * 4);
    f32x4 a2 = *(const f32x4*)(va + 256 + lane * 4);
    const int row0 = blockIdx.x * 32 + w * 8;
#pragma unroll 1
    for (int rr = 0; rr < 8; ++rr) {
        const int row = row0 + rr;
        f32x4 hv = *(const f32x4*)(x + (size_t)row * F_DIM + lane * 4);
        float p1 = hv[0] * a1[0] + hv[1] * a1[1] + hv[2] * a1[2] + hv[3] * a1[3];
        float p2 = hv[0] * a2[0] + hv[1] * a2[1] + hv[2] * a2[2] + hv[3] * a2[3];
#pragma unroll
        for (int o = 32; o; o >>= 1) { p1 += __shfl_xor(p1, o); p2 += __shfl_xor(p2, o); }
        if (lane == 0) { s1[row] = p1; s2[row] = p2; }
    }
}

// ------------- Kernel 2: fused masked softmax + PV (ONLINE MAX, r4-proven)
// grid 1024 = 512 row-blocks x 2 FEATURE halves; 256 thr = 4 waves = 4 key-chunks.
// Round-4-proven online softmax (NEG_INF masking, running m/l, rescale bcast),
// mask bits + 32-key step + 4-way flash merge (round-2/3-proven epilogue).
__global__ __launch_bounds__(256) void k2_attn(const unsigned* __restrict__ mask32,
                                               const unsigned short* __restrict__ hT,
                                               const float* __restrict__ s1,
                                               const float* __restrict__ s2,
                                               float* __restrict__ out) {
    __shared__ float mlbuf[2][4][16];           // [m|l][wc][row]
    __shared__ float accbuf[3][16][132];        // [wc-1][row][feat] (+4 pad)

    const int tid = threadIdx.x;
    const int lane = tid & 63;
    const int wc = tid >> 6;                    // 0..3 key-chunk
    const int lane15 = lane & 15, kg = lane >> 4, koff = kg * 8;
    const int rowblk = (int)blockIdx.x >> 1;
    const int fh = (int)blockIdx.x & 1;
    const int row0 = rowblk * 16;
    const int mrow = row0 + lane15;
    const int fb = fh * 128;
    const int kbase = wc * 2048;                // each wave owns 2048 keys
    const float si = s1[mrow];
    const unsigned* __restrict__ mrow32 = mask32 + (size_t)mrow * 256;

    f32x4 acc[8];
#pragma unroll
    for (int nt = 0; nt < 8; ++nt) { f32x4 z = {0.f, 0.f, 0.f, 0.f}; acc[nt] = z; }
    float m_run = NEG_INF_F, l_run = 0.0f;

    unsigned mw = mrow32[kbase >> 5];
    f32x4 svA = *(const f32x4*)(s2 + kbase + koff);
    f32x4 svB = *(const f32x4*)(s2 + kbase + koff + 4);

#pragma unroll 1
    for (int it = 0; it < 64; ++it) {           // 32 keys per step
        const int k0 = kbase + it * 32;
        const int kn = (it == 63) ? kbase : (k0 + 32);
        const unsigned mw_n = mrow32[kn >> 5];
        const f32x4 svA_n = *(const f32x4*)(s2 + kn + koff);
        const f32x4 svB_n = *(const f32x4*)(s2 + kn + koff + 4);

        s16x8 bfr[8];
#pragma unroll
        for (int nt = 0; nt < 8; ++nt)
            bfr[nt] = *(const s16x8*)(hT + (size_t)(fb + nt * 16 + lane15) * N_ROWS + k0 + koff);

        const unsigned bb = (mw >> koff) & 0xffu;
        float ev[8];
        {
            float t;
            t = si + svA[0]; t = fmaxf(t, 0.2f * t); ev[0] = (bb & 1u)   ? t : NEG_INF_F;
            t = si + svA[1]; t = fmaxf(t, 0.2f * t); ev[1] = (bb & 2u)   ? t : NEG_INF_F;
            t = si + svA[2]; t = fmaxf(t, 0.2f * t); ev[2] = (bb & 4u)   ? t : NEG_INF_F;
            t = si + svA[3]; t = fmaxf(t, 0.2f * t); ev[3] = (bb & 8u)   ? t : NEG_INF_F;
            t = si + svB[0]; t = fmaxf(t, 0.2f * t); ev[4] = (bb & 16u)  ? t : NEG_INF_F;
            t = si + svB[1]; t = fmaxf(t, 0.2f * t); ev[5] = (bb & 32u)  ? t : NEG_INF_F;
            t = si + svB[2]; t = fmaxf(t, 0.2f * t); ev[6] = (bb & 64u)  ? t : NEG_INF_F;
            t = si + svB[3]; t = fmaxf(t, 0.2f * t); ev[7] = (bb & 128u) ? t : NEG_INF_F;
        }
        float tm = ev[0];
#pragma unroll
        for (int i = 1; i < 8; ++i) tm = fmaxf(tm, ev[i]);
        tm = fmaxf(tm, __shfl_xor(tm, 16));     // reduce across the 4 kg groups
        tm = fmaxf(tm, __shfl_xor(tm, 32));
        const float m_new = fmaxf(m_run, tm);
        const bool upd = m_new > m_run;
        const float sc = exp2f((m_run - m_new) * LOG2E_F);
        float pv[8];
        float ts = 0.0f;
#pragma unroll
        for (int i = 0; i < 8; ++i) { pv[i] = exp2f((ev[i] - m_new) * LOG2E_F); ts += pv[i]; }
        ts += __shfl_xor(ts, 16);
        ts += __shfl_xor(ts, 32);
        l_run = l_run * sc + ts;
        m_run = m_new;
        if (__any(upd)) {
#pragma unroll
            for (int r = 0; r < 4; ++r) {
                const float scr = __shfl(sc, kg * 4 + r);
#pragma unroll
                for (int nt = 0; nt < 8; ++nt) acc[nt][r] *= scr;
            }
        }
        s16x8 af;
#pragma unroll
        for (int j = 0; j < 8; ++j) af[j] = (short)f2bf(pv[j]);

#pragma unroll
        for (int nt = 0; nt < 8; ++nt)
            acc[nt] = __builtin_amdgcn_mfma_f32_16x16x32_bf16(af, bfr[nt], acc[nt], 0, 0, 0);

        mw = mw_n; svA = svA_n; svB = svB_n;
    }

    // ---- 4-way flash merge across key-chunks (round-2/3-proven) ----
    if (kg == 0) {
        mlbuf[0][wc][lane15] = m_run;
        mlbuf[1][wc][lane15] = l_run;
    }
    __syncthreads();

    float myscale[4], linv[4];
#pragma unroll
    for (int r = 0; r < 4; ++r) {
        const int dr = kg * 4 + r;              // D-layout row this lane owns
        const float m0 = mlbuf[0][0][dr], m1 = mlbuf[0][1][dr];
        const float m2 = mlbuf[0][2][dr], m3 = mlbuf[0][3][dr];
        const float ms = fmaxf(fmaxf(m0, m1), fmaxf(m2, m3));
        const float e0 = exp2f((m0 - ms) * LOG2E_F);
        const float e1 = exp2f((m1 - ms) * LOG2E_F);
        const float e2 = exp2f((m2 - ms) * LOG2E_F);
        const float e3 = exp2f((m3 - ms) * LOG2E_F);
        const float lt = e0 * mlbuf[1][0][dr] + e1 * mlbuf[1][1][dr]
                       + e2 * mlbuf[1][2][dr] + e3 * mlbuf[1][3][dr];
        const float mo = mlbuf[0][wc][dr];      // own max (LDS read, runtime wc ok)
        myscale[r] = exp2f((mo - ms) * LOG2E_F);
        linv[r] = 1.0f / lt;
    }
#pragma unroll
    for (int r = 0; r < 4; ++r)
#pragma unroll
        for (int nt = 0; nt < 8; ++nt) acc[nt][r] *= myscale[r];

    if (wc > 0) {
#pragma unroll
        for (int r = 0; r < 4; ++r)
#pragma unroll
            for (int nt = 0; nt < 8; ++nt)
                accbuf[wc - 1][kg * 4 + r][nt * 16 + lane15] = acc[nt][r];
    }
    __syncthreads();

    if (wc == 0) {
#pragma unroll
        for (int r = 0; r < 4; ++r) {
            const int dr = kg * 4 + r;
            float* orow_p = out + (size_t)(row0 + dr) * F_DIM + fb + lane15;
#pragma unroll
            for (int nt = 0; nt < 8; ++nt) {
                const float v = acc[nt][r] + accbuf[0][dr][nt * 16 + lane15]
                              + accbuf[1][dr][nt * 16 + lane15]
                              + accbuf[2][dr][nt * 16 + lane15];
                orow_p[nt * 16] = v * linv[r];
            }
        }
    }
}

extern "C" void kernel_launch(void* const* d_in, const int* in_sizes, int n_in,
                              void* d_out, int out_size, void* d_ws, size_t ws_size,
                              hipStream_t stream) {
    (void)in_sizes; (void)n_in; (void)out_size; (void)ws_size;
    const float* x  = (const float*)d_in[0];
    const int*  adj = (const int*)d_in[1];
    const float* W  = (const float*)d_in[2];
    const float* a  = (const float*)d_in[3];
    float* out = (float*)d_out;
    char* ws = (char*)d_ws;
    // total ws use: 12.13 MB
    unsigned short* hT = (unsigned short*)ws;                       // 4 MB  [256][8192] bf16
    float* s1 = (float*)(ws + (4 << 20));                           // 32 KB
    float* s2 = (float*)(ws + (4 << 20) + (32 << 10));              // 32 KB
    float* va = (float*)(ws + (4 << 20) + (64 << 10));              // 2 KB  [2][256]
    unsigned* mk = (unsigned*)(ws + (4 << 20) + (128 << 10));       // 8 MB [8192][256] u32

    k0_pack<<<2048, 256, 0, stream>>>(adj, mk);
    k1_gemm<<<512, 256, 0, stream>>>(x, W, hT);
    kva<<<2, 256, 0, stream>>>(W, a, va);
    k1b_s<<<256, 256, 0, stream>>>(x, va, s1, s2);
    k2_attn<<<1024, 256, 0, stream>>>(mk, hT, s1, s2, out);
}